// Round 6
// baseline (304.289 us; speedup 1.0000x reference)
//
#include <hip/hip_runtime.h>
#include <hip/hip_bf16.h>
#include <cfloat>
#include <climits>

typedef short  short8v __attribute__((ext_vector_type(8)));
typedef float  f32x4   __attribute__((ext_vector_type(4)));

#define NQ    128   // queries (fixed by problem)
#define SR    16    // rows per strip (one MFMA A-tile)
#define SPB   8     // strips per block
#define RPB   (SR * SPB)   // 128 rows per block
#define EMIT  3     // candidates per query per block
#define K2    6     // per-thread top-k in phase 2 stream scan
#define KSEL  24    // approx top-K kept for exact rescore
#define KK    10    // final k

__device__ __forceinline__ bool pair_less(float d1, int i1, float d2, int i2) {
    return (d1 < d2) || (d1 == d2 && i1 < i2);
}

__device__ __forceinline__ unsigned pk2(float a, float b) {
    union { __hip_bfloat162 h; unsigned u; } cv;
    cv.h = __float22bfloat162_rn(make_float2(a, b));
    return cv.u;
}
__device__ __forceinline__ short8v pack8(float4 a, float4 b) {
    union { unsigned u[4]; short8v s; } cv;
    cv.u[0] = pk2(a.x, a.y); cv.u[1] = pk2(a.z, a.w);
    cv.u[2] = pk2(b.x, b.y); cv.u[3] = pk2(b.z, b.w);
    return cv.s;
}

// top-2 insert, key-only strict < (stream is ascending-idx => stable ties)
__device__ __forceinline__ void ins2(float (&d)[2], int (&ix)[2], float key, int idx) {
    if (!(key < d[1])) return;
    d[1] = key; ix[1] = idx;
    bool sw = d[1] < d[0];
    float a = d[0], b = d[1]; int ai = ix[0], bi2 = ix[1];
    d[0] = sw ? b : a; ix[0] = sw ? bi2 : ai;
    d[1] = sw ? a : b; ix[1] = sw ? ai : bi2;
}

// capacity-3 (key,idx)-ordered insert for the cross-lane merge
__device__ __forceinline__ void ins3p(float (&d)[3], int (&ix)[3], float key, int idx) {
    if (!pair_less(key, idx, d[2], ix[2])) return;
    d[2] = key; ix[2] = idx;
#pragma unroll
    for (int j = 2; j > 0; --j) {
        float a = d[j - 1], b = d[j]; int ai = ix[j - 1], bi2 = ix[j];
        bool sw = pair_less(b, bi2, a, ai);
        d[j - 1] = sw ? b : a; ix[j - 1] = sw ? bi2 : ai;
        d[j]     = sw ? a : b; ix[j]     = sw ? ai : bi2;
    }
}

__device__ __forceinline__ void ins6(float (&d)[K2], int (&ix)[K2], float key, int idx) {
    if (!pair_less(key, idx, d[K2 - 1], ix[K2 - 1])) return;
    d[K2 - 1] = key; ix[K2 - 1] = idx;
#pragma unroll
    for (int j = K2 - 1; j > 0; --j) {
        float a = d[j - 1], b = d[j]; int ai = ix[j - 1], bi2 = ix[j];
        bool sw = pair_less(b, bi2, a, ai);
        d[j - 1] = sw ? b : a; ix[j - 1] = sw ? bi2 : ai;
        d[j]     = sw ? a : b; ix[j]     = sw ? ai : bi2;
    }
}

__device__ __forceinline__ void argmin64(float& k, int& i, int& l) {
#pragma unroll
    for (int off = 32; off; off >>= 1) {
        float ok = __shfl_xor(k, off);
        int   oi = __shfl_xor(i, off);
        int   ol = __shfl_xor(l, off);
        bool take = pair_less(ok, oi, k, i) || (ok == k && oi == i && ol < l);
        k = take ? ok : k; i = take ? oi : i; l = take ? ol : l;
    }
}

// ---------------- Phase 1: 1-wave blocks, no LDS, no barriers ---------------
// Each wave owns 128 pool rows (8 strips of 16) and scores them against all
// 128 queries. A-fragments load DIRECTLY from global in MFMA lane layout
// (lane m=lane&15 reads dims [g*8,+8) and [32+g*8,+8) of its row — the two
// instruction pairs coalesce to dense 2KB row-segments). Convert in-register,
// psq via cross-lane shuffles, 16 MFMAs/strip vs resident B-fragments.
__global__ __launch_bounds__(64, 3) void phase1(
        const float* __restrict__ x, const float* __restrict__ pool_x,
        float2* __restrict__ cand, int N, int nblocks) {
    const int lane = threadIdx.x;          // 64-thread = 1-wave blocks
    const int c = lane & 15, g = lane >> 4;
    const int blk = blockIdx.x;
    const long brow = (long)blk * RPB;

    // B fragments: B'[k][q] = bf16(-2 x[q][k]); n=lane&15, k=g*8+j. 64 VGPRs.
    short8v bfrag[8][2];
#pragma unroll
    for (int tt = 0; tt < 8; ++tt)
#pragma unroll
        for (int ks = 0; ks < 2; ++ks) {
            const float* xp = x + (tt * 16 + c) * 64 + ks * 32 + g * 8;
            float4 u0 = *(const float4*)xp;
            float4 u1 = *(const float4*)(xp + 4);
            u0.x *= -2.f; u0.y *= -2.f; u0.z *= -2.f; u0.w *= -2.f;
            u1.x *= -2.f; u1.y *= -2.f; u1.z *= -2.f; u1.w *= -2.f;
            bfrag[tt][ks] = pack8(u0, u1);
        }

    float bd[8][2]; int bi[8][2];          // per-lane top-2 per query tile
#pragma unroll
    for (int tt = 0; tt < 8; ++tt) {
        bd[tt][0] = FLT_MAX; bd[tt][1] = FLT_MAX;
        bi[tt][0] = INT_MAX; bi[tt][1] = INT_MAX;
    }

    float4 nf0, nf1, nf2, nf3;             // distance-1 prefetch (16 VGPR)
    auto LOADS = [&](int s) {
        long r = brow + (long)s * SR + c;
        if (r > (long)N - 1) r = (long)N - 1;
        const float* pr = pool_x + r * 64 + g * 8;
        nf0 = *(const float4*)pr;
        nf1 = *(const float4*)(pr + 4);
        nf2 = *(const float4*)(pr + 32);
        nf3 = *(const float4*)(pr + 36);
    };
    LOADS(0);

#pragma unroll
    for (int s = 0; s < SPB; ++s) {
        float4 f0 = nf0, f1 = nf1, f2 = nf2, f3 = nf3;
        if (s + 1 < SPB) LOADS(s + 1);

        // psq: this lane's 16 dims, reduced across the 4 g-lanes of row c
        float ps = f0.x * f0.x + f0.y * f0.y + f0.z * f0.z + f0.w * f0.w
                 + f1.x * f1.x + f1.y * f1.y + f1.z * f1.z + f1.w * f1.w
                 + f2.x * f2.x + f2.y * f2.y + f2.z * f2.z + f2.w * f2.w
                 + f3.x * f3.x + f3.y * f3.y + f3.z * f3.z + f3.w * f3.w;
        ps += __shfl_xor(ps, 16);
        ps += __shfl_xor(ps, 32);
        if (brow + (long)s * SR + c >= N) ps = __builtin_inff();  // OOB never wins

        f32x4 psqv;                        // D-layout rows g*4+r
#pragma unroll
        for (int r = 0; r < 4; ++r) psqv[r] = __shfl(ps, g * 4 + r);

        short8v a0 = pack8(f0, f1);        // k = 0..31
        short8v a1 = pack8(f2, f3);        // k = 32..63
        const int rowb = (int)brow + s * SR + g * 4;

#pragma unroll
        for (int tt = 0; tt < 8; ++tt) {
            f32x4 acc = __builtin_amdgcn_mfma_f32_16x16x32_bf16(a0, bfrag[tt][0], psqv, 0, 0, 0);
            acc = __builtin_amdgcn_mfma_f32_16x16x32_bf16(a1, bfrag[tt][1], acc, 0, 0, 0);
            float mn = fminf(fminf(acc[0], acc[1]), fminf(acc[2], acc[3]));
            if (mn < bd[tt][1]) {
#pragma unroll
                for (int r = 0; r < 4; ++r) ins2(bd[tt], bi[tt], acc[r], rowb + r);
            }
        }
    }

    // End merge: butterfly over the 4 g-lanes (capacity 3 — union of per-lane
    // top-2s contains block top-3 unless 3 block-top entries share one lane
    // subset, which the phase-2 KSEL margin further insures). Lanes g<3 emit.
#pragma unroll
    for (int tt = 0; tt < 8; ++tt) {
        float md[3] = {bd[tt][0], bd[tt][1], FLT_MAX};
        int   mi[3] = {bi[tt][0], bi[tt][1], INT_MAX};
#pragma unroll
        for (int m = 16; m <= 32; m <<= 1) {
            float od[3]; int oi[3];
#pragma unroll
            for (int j = 0; j < 3; ++j) { od[j] = __shfl_xor(md[j], m); oi[j] = __shfl_xor(mi[j], m); }
#pragma unroll
            for (int j = 0; j < 3; ++j) ins3p(md, mi, od[j], oi[j]);
        }
        if (g < 3) {
            int q = tt * 16 + c;
            cand[(size_t)q * nblocks * EMIT + blk * EMIT + g] =
                make_float2(md[g], __int_as_float(mi[g]));
        }
    }
}

// ---------------- Phase 2: merge -> approx top-24 -> exact rescore -> top-10
__global__ __launch_bounds__(256) void phase2(
        const float2* __restrict__ cand, const float* __restrict__ x,
        const float* __restrict__ pool_x, const float* __restrict__ pool_y,
        float* __restrict__ out, int nblocks, int N) {
    __shared__ float xs[64];
    __shared__ float wd[4 * KSEL]; __shared__ int wi[4 * KSEL];
    __shared__ float sd[KSEL];     __shared__ int si[KSEL];
    __shared__ float rk[64];
    __shared__ int   fi[KK];

    const int t = threadIdx.x, wave = t >> 6, lane = t & 63;
    const int q = blockIdx.x;
    if (t < 64) xs[t] = x[q * 64 + t];

    const int M = nblocks * EMIT;
    float d[K2]; int ix[K2];
#pragma unroll
    for (int j = 0; j < K2; ++j) { d[j] = FLT_MAX; ix[j] = INT_MAX; }

    const float2* cq = cand + (size_t)q * M;
    for (int m = t; m < M; m += 256) {
        float2 e = cq[m];
        ins6(d, ix, e.x, __float_as_int(e.y));
    }

    // per-wave extraction of its top-KSEL
    for (int r = 0; r < KSEL; ++r) {
        float mk = d[0]; int mi = ix[0]; int ml = lane;
        argmin64(mk, mi, ml);
        if (lane == ml) {
#pragma unroll
            for (int j = 0; j < K2 - 1; ++j) { d[j] = d[j + 1]; ix[j] = ix[j + 1]; }
            d[K2 - 1] = FLT_MAX; ix[K2 - 1] = INT_MAX;
        }
        if (lane == 0) { wd[wave * KSEL + r] = mk; wi[wave * KSEL + r] = mi; }
    }
    __syncthreads();

    // wave 0 merges 4xKSEL=96 -> global approx top-KSEL
    if (wave == 0) {
        float e0 = wd[lane]; int e0i = wi[lane];
        float e1 = (lane + 64 < 4 * KSEL) ? wd[lane + 64] : FLT_MAX;
        int  e1i = (lane + 64 < 4 * KSEL) ? wi[lane + 64] : INT_MAX;
        if (pair_less(e1, e1i, e0, e0i)) {
            float tf = e0; e0 = e1; e1 = tf;
            int   ti = e0i; e0i = e1i; e1i = ti;
        }
        for (int r = 0; r < KSEL; ++r) {
            float mk = e0; int mi = e0i; int ml = lane;
            argmin64(mk, mi, ml);
            if (lane == ml) { e0 = e1; e0i = e1i; e1 = FLT_MAX; e1i = INT_MAX; }
            if (lane == 0) { sd[r] = mk; si[r] = mi; }
        }
    }
    __syncthreads();

    // exact fp32 rescore of the KSEL survivors
    if (t < 64) {
        float key = FLT_MAX;
        if (t < KSEL) {
            int idx = si[t];
            if (idx >= 0 && idx < N) {
                const float4* pr = (const float4*)(pool_x + (size_t)idx * 64);
                const float4* xv = (const float4*)xs;
                float psq = 0.f, dot = 0.f;
#pragma unroll
                for (int k4 = 0; k4 < 16; ++k4) {
                    float4 p = pr[k4]; float4 xw = xv[k4];
                    psq += p.x * p.x + p.y * p.y + p.z * p.z + p.w * p.w;
                    dot += p.x * xw.x + p.y * xw.y + p.z * xw.z + p.w * xw.w;
                }
                key = psq - 2.0f * dot;
            }
        }
        rk[t] = key;
    }
    __syncthreads();

    // exact top-10 by (key, idx)
    if (wave == 0) {
        float mykey = rk[lane];
        int myidx = (lane < KSEL) ? si[lane] : INT_MAX;
        for (int r = 0; r < KK; ++r) {
            float mk = mykey; int mi = myidx; int ml = lane;
            argmin64(mk, mi, ml);
            if (lane == ml) { mykey = FLT_MAX; myidx = INT_MAX; }
            if (lane == 0) fi[r] = mi;
        }
    }
    __syncthreads();

    // gather output rows: [q][j][0:64]=pool_x[idx], [q][j][64]=pool_y[idx]
    for (int e = t; e < KK * 65; e += 256) {
        int j = e / 65, cdim = e - j * 65;
        int idx = fi[j];
        out[(size_t)q * (KK * 65) + e] = (cdim < 64) ? pool_x[(size_t)idx * 64 + cdim]
                                                     : pool_y[idx];
    }
}

extern "C" void kernel_launch(void* const* d_in, const int* in_sizes, int n_in,
                              void* d_out, int out_size, void* d_ws, size_t ws_size,
                              hipStream_t stream) {
    const float* x      = (const float*)d_in[0];
    const float* pool_x = (const float*)d_in[1];
    const float* pool_y = (const float*)d_in[2];
    const int N = in_sizes[1] / 64;

    const int nblocks = (N + RPB - 1) / RPB;   // 3907 at N=500000

    float2* cand = (float2*)d_ws;              // [NQ][nblocks*EMIT] {key, idx}

    hipLaunchKernelGGL(phase1, dim3(nblocks), dim3(64), 0, stream,
                       x, pool_x, cand, N, nblocks);
    hipLaunchKernelGGL(phase2, dim3(NQ), dim3(256), 0, stream,
                       cand, x, pool_x, pool_y, (float*)d_out, nblocks, N);
}

// Round 7
// 258.106 us; speedup vs baseline: 1.1789x; 1.1789x over previous
//
#include <hip/hip_runtime.h>
#include <hip/hip_bf16.h>
#include <cfloat>
#include <climits>

typedef short  short8v __attribute__((ext_vector_type(8)));
typedef float  f32x4   __attribute__((ext_vector_type(4)));

#define NQ    128   // queries (fixed by problem)
#define SR    16    // rows per strip (one MFMA A-tile)
#define SPW   8     // strips per wave (128 rows per wave-chunk)
#define RPC   (SR * SPW)     // 128 rows per chunk
#define EMIT  3     // candidates per query per chunk
#define K2    6     // per-thread top-k in phase 2 stream scan
#define KSEL  24    // approx top-K kept for exact rescore
#define KK    10    // final k

__device__ __forceinline__ bool pair_less(float d1, int i1, float d2, int i2) {
    return (d1 < d2) || (d1 == d2 && i1 < i2);
}

__device__ __forceinline__ unsigned pk2(float a, float b) {
    union { __hip_bfloat162 h; unsigned u; } cv;
    cv.h = __float22bfloat162_rn(make_float2(a, b));
    return cv.u;
}
__device__ __forceinline__ short8v pack8(float4 a, float4 b) {
    union { unsigned u[4]; short8v s; } cv;
    cv.u[0] = pk2(a.x, a.y); cv.u[1] = pk2(a.z, a.w);
    cv.u[2] = pk2(b.x, b.y); cv.u[3] = pk2(b.z, b.w);
    return cv.s;
}

// top-2 insert, key-only strict < (stream ascending-idx => stable ties)
__device__ __forceinline__ void ins2(float (&d)[2], int (&ix)[2], float key, int idx) {
    if (!(key < d[1])) return;
    d[1] = key; ix[1] = idx;
    bool sw = d[1] < d[0];
    float a = d[0], b = d[1]; int ai = ix[0], bi2 = ix[1];
    d[0] = sw ? b : a; ix[0] = sw ? bi2 : ai;
    d[1] = sw ? a : b; ix[1] = sw ? ai : bi2;
}

// capacity-3 (key,idx)-ordered insert for the cross-lane merge
__device__ __forceinline__ void ins3p(float (&d)[3], int (&ix)[3], float key, int idx) {
    if (!pair_less(key, idx, d[2], ix[2])) return;
    d[2] = key; ix[2] = idx;
#pragma unroll
    for (int j = 2; j > 0; --j) {
        float a = d[j - 1], b = d[j]; int ai = ix[j - 1], bi2 = ix[j];
        bool sw = pair_less(b, bi2, a, ai);
        d[j - 1] = sw ? b : a; ix[j - 1] = sw ? bi2 : ai;
        d[j]     = sw ? a : b; ix[j]     = sw ? ai : bi2;
    }
}

__device__ __forceinline__ void ins6(float (&d)[K2], int (&ix)[K2], float key, int idx) {
    if (!pair_less(key, idx, d[K2 - 1], ix[K2 - 1])) return;
    d[K2 - 1] = key; ix[K2 - 1] = idx;
#pragma unroll
    for (int j = K2 - 1; j > 0; --j) {
        float a = d[j - 1], b = d[j]; int ai = ix[j - 1], bi2 = ix[j];
        bool sw = pair_less(b, bi2, a, ai);
        d[j - 1] = sw ? b : a; ix[j - 1] = sw ? bi2 : ai;
        d[j]     = sw ? a : b; ix[j]     = sw ? ai : bi2;
    }
}

__device__ __forceinline__ void argmin64(float& k, int& i, int& l) {
#pragma unroll
    for (int off = 32; off; off >>= 1) {
        float ok = __shfl_xor(k, off);
        int   oi = __shfl_xor(i, off);
        int   ol = __shfl_xor(l, off);
        bool take = pair_less(ok, oi, k, i) || (ok == k && oi == i && ol < l);
        k = take ? ok : k; i = take ? oi : i; l = take ? ol : l;
    }
}

// ---------------- Phase 1: no LDS, no barriers, psq via matrix unit ---------
// Block = 4 waves. Wave wv: queries [qbase,qbase+64) (qbase = (wv>>1)*64),
// chunk = blk*2 + (wv&1) (128 rows). Rows loaded directly in MFMA A-layout;
// per-lane partial psq enters the accumulator through one extra MFMA
// (A2 slot k=g*8 = partial, B2 = 1 at k%8==0) -> zero DS ops in the loop.
__global__ __launch_bounds__(256, 4) void phase1(
        const float* __restrict__ x, const float* __restrict__ pool_x,
        float2* __restrict__ cand, int N, int nchunks) {
    const int t = threadIdx.x, wv = t >> 6, lane = t & 63;
    const int c = lane & 15, g = lane >> 4;
    const int qbase = (wv >> 1) * 64;
    const int chunk = blockIdx.x * 2 + (wv & 1);
    const long brow = (long)chunk * RPC;

    // B fragments: 4 tiles x 16 queries; B'[k][q]=bf16(-2 x[q][k]). 32 VGPRs.
    short8v bfrag[4][2];
#pragma unroll
    for (int tt = 0; tt < 4; ++tt)
#pragma unroll
        for (int ks = 0; ks < 2; ++ks) {
            const float* xp = x + (qbase + tt * 16 + c) * 64 + ks * 32 + g * 8;
            float4 u0 = *(const float4*)xp;
            float4 u1 = *(const float4*)(xp + 4);
            u0.x *= -2.f; u0.y *= -2.f; u0.z *= -2.f; u0.w *= -2.f;
            u1.x *= -2.f; u1.y *= -2.f; u1.z *= -2.f; u1.w *= -2.f;
            bfrag[tt][ks] = pack8(u0, u1);
        }

    // B2: 1.0 at k in {0,8,16,24} -> every lane holds {1,0,0,0,0,0,0,0}
    short8v b2 = {0, 0, 0, 0, 0, 0, 0, 0};
    b2[0] = (short)0x3F80;

    float bd[4][2]; int bi[4][2];
#pragma unroll
    for (int tt = 0; tt < 4; ++tt) {
        bd[tt][0] = FLT_MAX; bd[tt][1] = FLT_MAX;
        bi[tt][0] = INT_MAX; bi[tt][1] = INT_MAX;
    }

    float4 buf[2][4];   // double-buffered register prefetch
    auto LOAD = [&](int s, int b) {
        long r = brow + (long)s * SR + c;
        if (r > (long)N - 1) r = (long)N - 1;
        const float* pr = pool_x + r * 64 + g * 8;
        buf[b][0] = *(const float4*)pr;
        buf[b][1] = *(const float4*)(pr + 4);
        buf[b][2] = *(const float4*)(pr + 32);
        buf[b][3] = *(const float4*)(pr + 36);
    };
    LOAD(0, 0);

#pragma unroll
    for (int s = 0; s < SPW; ++s) {
        const int b = s & 1;
        if (s + 1 < SPW) LOAD(s + 1, b ^ 1);   // issue before buf[b] use
        float4 f0 = buf[b][0], f1 = buf[b][1], f2 = buf[b][2], f3 = buf[b][3];

        // partial psq over this lane's 16 dims (fp32), -> bf16 into A2 slot 0
        float ps = f0.x * f0.x + f0.y * f0.y + f0.z * f0.z + f0.w * f0.w
                 + f1.x * f1.x + f1.y * f1.y + f1.z * f1.z + f1.w * f1.w
                 + f2.x * f2.x + f2.y * f2.y + f2.z * f2.z + f2.w * f2.w
                 + f3.x * f3.x + f3.y * f3.y + f3.z * f3.z + f3.w * f3.w;
        if (brow + (long)s * SR + c >= N) ps = __builtin_inff();  // OOB never wins

        short8v a2 = {0, 0, 0, 0, 0, 0, 0, 0};
        union { unsigned u; short s2[2]; } pv; pv.u = pk2(ps, 0.f);
        a2[0] = pv.s2[0];

        short8v a0 = pack8(f0, f1);        // k = 0..31
        short8v a1 = pack8(f2, f3);        // k = 32..63

        f32x4 zc = {0.f, 0.f, 0.f, 0.f};
        f32x4 pacc = __builtin_amdgcn_mfma_f32_16x16x32_bf16(a2, b2, zc, 0, 0, 0);

        const int rowb = (int)brow + s * SR + g * 4;
#pragma unroll
        for (int tt = 0; tt < 4; ++tt) {
            f32x4 acc = __builtin_amdgcn_mfma_f32_16x16x32_bf16(a0, bfrag[tt][0], pacc, 0, 0, 0);
            acc = __builtin_amdgcn_mfma_f32_16x16x32_bf16(a1, bfrag[tt][1], acc, 0, 0, 0);
            float mn = fminf(fminf(acc[0], acc[1]), fminf(acc[2], acc[3]));
            if (mn < bd[tt][1]) {
#pragma unroll
                for (int r = 0; r < 4; ++r) ins2(bd[tt], bi[tt], acc[r], rowb + r);
            }
        }
    }

    // End merge: butterfly over the 4 g-lanes (capacity 3), lanes g<3 emit.
    // Layout [chunk][q][3] -> dense 1.5 KB per (chunk, q-half).
#pragma unroll
    for (int tt = 0; tt < 4; ++tt) {
        float md[3] = {bd[tt][0], bd[tt][1], FLT_MAX};
        int   mi[3] = {bi[tt][0], bi[tt][1], INT_MAX};
#pragma unroll
        for (int m = 16; m <= 32; m <<= 1) {
            float od[3]; int oi[3];
#pragma unroll
            for (int j = 0; j < 3; ++j) { od[j] = __shfl_xor(md[j], m); oi[j] = __shfl_xor(mi[j], m); }
#pragma unroll
            for (int j = 0; j < 3; ++j) ins3p(md, mi, od[j], oi[j]);
        }
        if (g < 3) {
            int q = qbase + tt * 16 + c;
            cand[((size_t)chunk * NQ + q) * EMIT + g] =
                make_float2(md[g], __int_as_float(mi[g]));
        }
    }
}

// ---------------- Phase 2: merge -> approx top-24 -> exact rescore -> top-10
__global__ __launch_bounds__(256) void phase2(
        const float2* __restrict__ cand, const float* __restrict__ x,
        const float* __restrict__ pool_x, const float* __restrict__ pool_y,
        float* __restrict__ out, int nchunks, int N) {
    __shared__ float xs[64];
    __shared__ float wd[4 * KSEL]; __shared__ int wi[4 * KSEL];
    __shared__ float sd[KSEL];     __shared__ int si[KSEL];
    __shared__ float rk[64];
    __shared__ int   fi[KK];

    const int t = threadIdx.x, wave = t >> 6, lane = t & 63;
    const int q = blockIdx.x;
    if (t < 64) xs[t] = x[q * 64 + t];

    float d[K2]; int ix[K2];
#pragma unroll
    for (int j = 0; j < K2; ++j) { d[j] = FLT_MAX; ix[j] = INT_MAX; }

    for (int ch = t; ch < nchunks; ch += 256) {
        const float2* e = cand + ((size_t)ch * NQ + q) * EMIT;
#pragma unroll
        for (int g2 = 0; g2 < EMIT; ++g2) {
            float2 v = e[g2];
            ins6(d, ix, v.x, __float_as_int(v.y));
        }
    }

    // per-wave extraction of its top-KSEL
    for (int r = 0; r < KSEL; ++r) {
        float mk = d[0]; int mi = ix[0]; int ml = lane;
        argmin64(mk, mi, ml);
        if (lane == ml) {
#pragma unroll
            for (int j = 0; j < K2 - 1; ++j) { d[j] = d[j + 1]; ix[j] = ix[j + 1]; }
            d[K2 - 1] = FLT_MAX; ix[K2 - 1] = INT_MAX;
        }
        if (lane == 0) { wd[wave * KSEL + r] = mk; wi[wave * KSEL + r] = mi; }
    }
    __syncthreads();

    // wave 0 merges 4xKSEL=96 -> global approx top-KSEL
    if (wave == 0) {
        float e0 = wd[lane]; int e0i = wi[lane];
        float e1 = (lane + 64 < 4 * KSEL) ? wd[lane + 64] : FLT_MAX;
        int  e1i = (lane + 64 < 4 * KSEL) ? wi[lane + 64] : INT_MAX;
        if (pair_less(e1, e1i, e0, e0i)) {
            float tf = e0; e0 = e1; e1 = tf;
            int   ti = e0i; e0i = e1i; e1i = ti;
        }
        for (int r = 0; r < KSEL; ++r) {
            float mk = e0; int mi = e0i; int ml = lane;
            argmin64(mk, mi, ml);
            if (lane == ml) { e0 = e1; e0i = e1i; e1 = FLT_MAX; e1i = INT_MAX; }
            if (lane == 0) { sd[r] = mk; si[r] = mi; }
        }
    }
    __syncthreads();

    // exact fp32 rescore of the KSEL survivors
    if (t < 64) {
        float key = FLT_MAX;
        if (t < KSEL) {
            int idx = si[t];
            if (idx >= 0 && idx < N) {
                const float4* pr = (const float4*)(pool_x + (size_t)idx * 64);
                const float4* xv = (const float4*)xs;
                float psq = 0.f, dot = 0.f;
#pragma unroll
                for (int k4 = 0; k4 < 16; ++k4) {
                    float4 p = pr[k4]; float4 xw = xv[k4];
                    psq += p.x * p.x + p.y * p.y + p.z * p.z + p.w * p.w;
                    dot += p.x * xw.x + p.y * xw.y + p.z * xw.z + p.w * xw.w;
                }
                key = psq - 2.0f * dot;
            }
        }
        rk[t] = key;
    }
    __syncthreads();

    // exact top-10 by (key, idx)
    if (wave == 0) {
        float mykey = rk[lane];
        int myidx = (lane < KSEL) ? si[lane] : INT_MAX;
        for (int r = 0; r < KK; ++r) {
            float mk = mykey; int mi = myidx; int ml = lane;
            argmin64(mk, mi, ml);
            if (lane == ml) { mykey = FLT_MAX; myidx = INT_MAX; }
            if (lane == 0) fi[r] = mi;
        }
    }
    __syncthreads();

    // gather output rows: [q][j][0:64]=pool_x[idx], [q][j][64]=pool_y[idx]
    for (int e = t; e < KK * 65; e += 256) {
        int j = e / 65, cdim = e - j * 65;
        int idx = fi[j];
        out[(size_t)q * (KK * 65) + e] = (cdim < 64) ? pool_x[(size_t)idx * 64 + cdim]
                                                     : pool_y[idx];
    }
}

extern "C" void kernel_launch(void* const* d_in, const int* in_sizes, int n_in,
                              void* d_out, int out_size, void* d_ws, size_t ws_size,
                              hipStream_t stream) {
    const float* x      = (const float*)d_in[0];
    const float* pool_x = (const float*)d_in[1];
    const float* pool_y = (const float*)d_in[2];
    const int N = in_sizes[1] / 64;

    const int nblocks = (N + 2 * RPC - 1) / (2 * RPC);  // 1954 at N=500000
    const int nchunks = nblocks * 2;                    // 3908

    float2* cand = (float2*)d_ws;   // [nchunks][NQ][EMIT] {key, idx-bits}

    hipLaunchKernelGGL(phase1, dim3(nblocks), dim3(256), 0, stream,
                       x, pool_x, cand, N, nchunks);
    hipLaunchKernelGGL(phase2, dim3(NQ), dim3(256), 0, stream,
                       cand, x, pool_x, pool_y, (float*)d_out, nchunks, N);
}